// Round 7
// baseline (315.407 us; speedup 1.0000x reference)
//
#include <hip/hip_runtime.h>
#include <hip/hip_bf16.h>
#include <stdint.h>

typedef __attribute__((ext_vector_type(4))) float f32x4;
typedef __attribute__((ext_vector_type(8))) short s16x8;

#define BARRIER() asm volatile("s_barrier" ::: "memory")
#define WAITV8()  asm volatile("s_waitcnt vmcnt(8)" ::: "memory")
#define WAITV0()  asm volatile("s_waitcnt vmcnt(0)" ::: "memory")
#define MFMA(a, b, c) __builtin_amdgcn_mfma_f32_16x16x32_bf16((a), (b), (c), 0, 0, 0)

__device__ __forceinline__ ushort f2bf(float f) {
  union { float f; uint32_t u; } v; v.f = f;
  uint32_t r = v.u + 0x7FFFu + ((v.u >> 16) & 1u);
  return (ushort)(r >> 16);
}

__device__ __forceinline__ void gload_lds16(const ushort* g, short* l) {
  __builtin_amdgcn_global_load_lds(
      (const __attribute__((address_space(1))) uint32_t*)g,
      (__attribute__((address_space(3))) uint32_t*)l, 16, 0, 0);
}

// generic bijective XCD chunk swizzle; valid when nwg % 8 == 0, q = nwg/8
__device__ __forceinline__ int xcd_swz(int flat, int q) {
  return (flat & 7) * q + (flat >> 3);
}

// Stage a 128x64 bf16 tile into LDS with 256 threads (4 loads/thread).
// LDS dest linear (global_load_lds requirement); T2 swizzle via permuted
// GLOBAL source 16B-slot: phys(r,s) holds global(r, s ^ (r&7)).
__device__ __forceinline__ void stage128(const ushort* __restrict__ g, int ld,
                                         int row0, int k0, short* lbase, int tid) {
  const int w  = tid >> 6;               // 0..3
  const int l  = tid & 63;
  const int lr = l >> 3;                 // row within 8-row group
  const int ls = l & 7;                  // physical 16B slot
  const ushort* gp = g + (size_t)(row0 + lr) * ld + k0 + ((ls ^ lr) << 3);
  short* lp = lbase + l * 8;
#pragma unroll
  for (int i = 0; i < 4; ++i) {
    const int R0 = w * 32 + i * 8;
    gload_lds16(gp + (size_t)R0 * ld, lp + R0 * 64);
  }
}

// 128x128 tile GEMM core: A[M,K]*Bt[N,K]^T, bf16, fp32 acc.
// 256 thr = 4 waves (2M x 2N), wave = 64x64 out = 4x4 frags of 16x16x32.
// A triple-buffered (depth-2 prefetch), B double-buffered: 80KB LDS ->
// 2 blocks/CU. Counted vmcnt(8) gate; raw s_barrier; stage A(X+2)@alpha,
// B(X+2)@beta. Ledger: entering alpha(X) outstanding = {A(X),B(X),A(X+1),
// B(X+1)} (16 loads); vmcnt(8) drains {A(X),B(X)}.
__device__ __forceinline__ void gemm_core(
    const ushort* __restrict__ A, int lda, const ushort* __restrict__ Bt, int ldb,
    int m0, int n0, int nk, short* lds, f32x4 acc[4][4])
{
  const int tid  = threadIdx.x;
  const int lane = tid & 63, wid = tid >> 6;
  const int wr = wid >> 1, wc = wid & 1;
  const int fr = lane & 15, kg = lane >> 4;
  const int s0  = (kg ^ (fr & 7)) << 3;        // swizzled slot offset (shorts)
  const int aro = (wr * 64 + fr) * 64;
  const int bro = (wc * 64 + fr) * 64;

  short* Ar  = lds;             // A(X)   (read)
  short* An1 = lds + 8192;      // A(X+1) (landed/landing)
  short* An2 = lds + 16384;     // A(X+2) (stage target)
  short* Br  = lds + 24576;     // B(X)   (read; restaged with B(X+2) at beta)
  short* Bn  = lds + 32768;     // B(X+1)

#pragma unroll
  for (int i = 0; i < 4; ++i)
#pragma unroll
    for (int j = 0; j < 4; ++j)
      acc[i][j] = (f32x4){0.f, 0.f, 0.f, 0.f};

  // prologue: A(0),B(0),A(1),B(1) in flight (16 loads/thread-group)
  stage128(A, lda, m0, 0, Ar, tid);
  stage128(Bt, ldb, n0, 0, Br, tid);
  if (nk > 1) {
    stage128(A, lda, m0, 64, An1, tid);
    stage128(Bt, ldb, n0, 64, Bn, tid);
  }

#pragma unroll 1
  for (int X = 0; X < nk; ++X) {
    // ---- phase alpha: gate tile X resident (keep {A,B}(X+1) in flight)
    if (X + 1 < nk) { WAITV8(); } else { WAITV0(); }
    BARRIER();
    if (X + 2 < nk) stage128(A, lda, m0, (X + 2) * 64, An2, tid);  // A(X+2)

    s16x8 b[4][2], a[2][2];
#pragma unroll
    for (int ni = 0; ni < 4; ++ni) {
      b[ni][0] = *(const s16x8*)(Br + bro + ni * 1024 + s0);
      b[ni][1] = *(const s16x8*)(Br + bro + ni * 1024 + (s0 ^ 32));
    }
#pragma unroll
    for (int mi = 0; mi < 2; ++mi) {
      a[mi][0] = *(const s16x8*)(Ar + aro + mi * 1024 + s0);
      a[mi][1] = *(const s16x8*)(Ar + aro + mi * 1024 + (s0 ^ 32));
    }
    __builtin_amdgcn_s_setprio(1);
#pragma unroll
    for (int mi = 0; mi < 2; ++mi)
#pragma unroll
      for (int ni = 0; ni < 4; ++ni) {
        acc[mi][ni] = MFMA(a[mi][0], b[ni][0], acc[mi][ni]);
        acc[mi][ni] = MFMA(a[mi][1], b[ni][1], acc[mi][ni]);
      }
    __builtin_amdgcn_s_setprio(0);

    // ---- phase beta: A rows 32-63 of wave panel; stage B(X+2) into Br's
    // region (B(X) reads all happened in alpha, sealed by this barrier).
    BARRIER();
    if (X + 2 < nk) stage128(Bt, ldb, n0, (X + 2) * 64, Br, tid);  // B(X+2)
#pragma unroll
    for (int mi = 0; mi < 2; ++mi) {
      a[mi][0] = *(const s16x8*)(Ar + aro + (2 + mi) * 1024 + s0);
      a[mi][1] = *(const s16x8*)(Ar + aro + (2 + mi) * 1024 + (s0 ^ 32));
    }
    __builtin_amdgcn_s_setprio(1);
#pragma unroll
    for (int mi = 0; mi < 2; ++mi)
#pragma unroll
      for (int ni = 0; ni < 4; ++ni) {
        acc[2 + mi][ni] = MFMA(a[mi][0], b[ni][0], acc[2 + mi][ni]);
        acc[2 + mi][ni] = MFMA(a[mi][1], b[ni][1], acc[2 + mi][ni]);
      }
    __builtin_amdgcn_s_setprio(0);

    // rotate buffers: A 3-cycle, B swap
    short* t = Ar; Ar = An1; An1 = An2; An2 = t;
    t = Br; Br = Bn; Bn = t;
  }
}

__global__ void cvt_x(const float* __restrict__ x, ushort* __restrict__ xb)
{
  const size_t i = (size_t)(blockIdx.x * 256 + threadIdx.x) * 4;
  const f32x4 t = *(const f32x4*)(x + i);
  uint2 pk;
  pk.x = (uint32_t)f2bf(t[0]) | ((uint32_t)f2bf(t[1]) << 16);
  pk.y = (uint32_t)f2bf(t[2]) | ((uint32_t)f2bf(t[3]) << 16);
  *(uint2*)(xb + i) = pk;
}

// wt[z][n][k] = bf16(w_z[k][n]);  z: 0=q_wei, 1=k_wei, 2=v_wei
__global__ void cvt_w(const float* __restrict__ kw, const float* __restrict__ qw,
                      const float* __restrict__ vw, ushort* __restrict__ wt)
{
  __shared__ float t[32][33];
  const float* w = (blockIdx.z == 0) ? qw : (blockIdx.z == 1) ? kw : vw;
  const int n0 = blockIdx.x * 32, k0 = blockIdx.y * 32;
  t[threadIdx.y][threadIdx.x] = w[(size_t)(k0 + threadIdx.y) * 1024 + n0 + threadIdx.x];
  __syncthreads();
  wt[(size_t)blockIdx.z * 1048576 + (size_t)(n0 + threadIdx.y) * 1024 + k0 + threadIdx.x] =
      f2bf(t[threadIdx.x][threadIdx.y]);
}

// N = 3072 (q|k|v), M = 16384. grid (24, 128) = 3072 blocks.
// Rectangular XCD map: 8 XCDs = 2 m-groups x 4 n-groups(6 tiles); within an
// XCD m streams (n innermost) -> working set = 1.5MB B-slice + ~0.5MB A << L2.
__global__ __launch_bounds__(256) void gemm_qkv_impl(
    const ushort* __restrict__ xb, const ushort* __restrict__ wt,
    ushort* __restrict__ q, ushort* __restrict__ k, ushort* __restrict__ vT)
{
  extern __shared__ short lds[];
  const int flat = blockIdx.x + 24 * blockIdx.y;
  const int xcd = flat & 7, c = flat >> 3;          // c in [0,384)
  const int mloc = c / 6, nloc = c - mloc * 6;
  const int m0 = ((xcd & 1) * 64 + mloc) * 128;
  const int n0 = ((xcd >> 1) * 6 + nloc) * 128;
  f32x4 acc[4][4];
  gemm_core(xb, 1024, wt, 1024, m0, n0, 16, lds, acc);

  const int lane = threadIdx.x & 63;
  const int wid = threadIdx.x >> 6;
  const int wr = wid >> 1, wc = wid & 1;
  const int q4 = (lane >> 4) << 2;
  const int fr = lane & 15;
  const int z  = n0 >> 10;                         // uniform per block
  const int cb = (n0 & 1023) + wc * 64 + fr;
  ushort* o = (z == 0) ? q : k;
#pragma unroll
  for (int mi = 0; mi < 4; ++mi)
#pragma unroll
    for (int ni = 0; ni < 4; ++ni)
#pragma unroll
      for (int j = 0; j < 4; ++j) {
        const int r = m0 + wr * 64 + mi * 16 + q4 + j;
        const int c2 = cb + ni * 16;
        const ushort hv = f2bf(acc[mi][ni][j]);
        if (z < 2) o[(size_t)r * 1024 + c2] = hv;
        else       vT[((size_t)(r >> 11) * 1024 + c2) * 2048 + (r & 2047)] = hv;
      }
}

// Fused S-GEMM + softmax-exp (no-max trick): writes unnormalized
// P~ = exp(qk/32 - 10) bf16 dense [b][2048][2048], accumulates row sums.
// grid (16 kt, 16 qt, 8 b) = 2048 blocks; one b per XCD; causal tile skip.
__global__ __launch_bounds__(256) void gemm_sp(
    const ushort* __restrict__ q, const ushort* __restrict__ k,
    ushort* __restrict__ P, float* __restrict__ sums)
{
  extern __shared__ short lds[];
  const int nf = xcd_swz(blockIdx.x + 16 * (blockIdx.y + 16 * blockIdx.z), 256);
  const int kt = nf & 15, qt = (nf >> 4) & 15, b = nf >> 8;
  if (kt > qt) return;  // causal: whole tile masked
  f32x4 acc[4][4];
  const ushort* qb = q + (size_t)b * (2048 * 1024);
  const ushort* kb = k + (size_t)b * (2048 * 1024);
  gemm_core(qb, 1024, kb, 1024, qt * 128, kt * 128, 16, lds, acc);
  __syncthreads();                          // staging LDS now dead; reuse below
  float* rowsum = (float*)lds;              // [2 wc][128 rows]

  const int tid  = threadIdx.x;
  const int lane = tid & 63, wid = tid >> 6;
  const int wr = wid >> 1, wc = wid & 1;
  const int q4 = (lane >> 4) << 2;
  const int fr = lane & 15;
  const int diag = (kt == qt);
  ushort* Pb = P + ((size_t)b << 22);

#pragma unroll
  for (int mi = 0; mi < 4; ++mi)
#pragma unroll
    for (int j = 0; j < 4; ++j) {
      const int rloc = wr * 64 + mi * 16 + q4 + j;       // row in tile
      const int rg   = qt * 128 + rloc;                   // global q index
      float s = 0.f;
#pragma unroll
      for (int ni = 0; ni < 4; ++ni) {
        const int cg = kt * 128 + wc * 64 + ni * 16 + fr; // global k index
        float e = __expf(acc[mi][ni][j] * 0.03125f - 10.f);
        if (diag && cg > rg) e = 0.f;
        s += e;
        Pb[(size_t)rg * 2048 + cg] = f2bf(e);
      }
      // reduce over the 16 fr lanes (this wave's 64-col stripe)
#pragma unroll
      for (int m = 1; m < 16; m <<= 1) s += __shfl_xor(s, m);
      if (fr == 0) rowsum[wc * 128 + rloc] = s;
    }
  __syncthreads();
  if (tid < 128) {
    const float tot = rowsum[tid] + rowsum[128 + tid];
    atomicAdd(&sums[b * 2048 + qt * 128 + tid], tot);
  }
}

// grid (8 ht, 16 qt, 8 b) = 1024 blocks; one b per XCD; K truncated causally;
// out = (P~ . V) / sums[row].
__global__ __launch_bounds__(256) void gemm_pv(
    const ushort* __restrict__ P, const ushort* __restrict__ vT,
    const float* __restrict__ sums, float* __restrict__ out)
{
  extern __shared__ short lds[];
  const int nf = xcd_swz(blockIdx.x + 8 * (blockIdx.y + 16 * blockIdx.z), 128);
  const int ht = nf & 7, qt = (nf >> 3) & 15, b = nf >> 7;
  f32x4 acc[4][4];
  const ushort* Pb = P  + ((size_t)b << 22);           // dense [2048][2048]
  const ushort* Vb = vT + (size_t)b * (1024 * 2048);
  gemm_core(Pb, 2048, Vb, 2048, qt * 128, ht * 128, (qt + 1) * 2, lds, acc);

  float* ob = out + (size_t)b * 2097152;
  const int lane = threadIdx.x & 63;
  const int wid = threadIdx.x >> 6;
  const int wr = wid >> 1, wc = wid & 1;
  const int r0 = qt * 128 + wr * 64 + ((lane >> 4) << 2);
  const int c0 = ht * 128 + wc * 64 + (lane & 15);
#pragma unroll
  for (int mi = 0; mi < 4; ++mi)
#pragma unroll
    for (int j = 0; j < 4; ++j) {
      const int r = r0 + mi * 16 + j;
      const float inv = 1.0f / sums[b * 2048 + r];
#pragma unroll
      for (int ni = 0; ni < 4; ++ni)
        ob[(size_t)r * 1024 + (c0 + ni * 16)] = acc[mi][ni][j] * inv;
    }
}

extern "C" void kernel_launch(void* const* d_in, const int* in_sizes, int n_in,
                              void* d_out, int out_size, void* d_ws, size_t ws_size,
                              hipStream_t stream)
{
  const float* x  = (const float*)d_in[0];
  const float* kw = (const float*)d_in[1];
  const float* qw = (const float*)d_in[2];
  const float* vw = (const float*)d_in[3];
  float* out = (float*)d_out;
  char* ws = (char*)d_ws;

  ushort* xb   = (ushort*)ws;                  // 32MB; aliases P~ (consumed first)
  ushort* P    = (ushort*)ws;                  // 64MB dense bf16 P~ [8][2048][2048]
  float*  sums = (float*)(ws + 67108864);      // 64KB row sums [8][2048]
  ushort* wt   = (ushort*)(ws + 67174400);     // 6MB  transposed bf16 weights [z][n][k]
  ushort* q    = (ushort*)(ws + 73465856);     // 32MB
  ushort* k    = (ushort*)(ws + 107020288);    // 32MB
  ushort* vT   = (ushort*)(ws + 140574720);    // 32MB [B][HS][T]

  const int LDSB = 81920;   // 80KB dynamic LDS (A x3 + B x2) -> 2 blocks/CU
  hipFuncSetAttribute((const void*)gemm_qkv_impl, hipFuncAttributeMaxDynamicSharedMemorySize, LDSB);
  hipFuncSetAttribute((const void*)gemm_sp,       hipFuncAttributeMaxDynamicSharedMemorySize, LDSB);
  hipFuncSetAttribute((const void*)gemm_pv,       hipFuncAttributeMaxDynamicSharedMemorySize, LDSB);

  hipMemsetAsync(sums, 0, 8 * 2048 * sizeof(float), stream);
  cvt_x<<<16384, 256, 0, stream>>>(x, xb);
  cvt_w<<<dim3(32, 32, 3), dim3(32, 32), 0, stream>>>(kw, qw, vw, wt);
  gemm_qkv_impl<<<dim3(24, 128), 256, LDSB, stream>>>(xb, wt, q, k, vT);
  gemm_sp<<<dim3(16, 16, 8), 256, LDSB, stream>>>(q, k, P, sums);
  gemm_pv<<<dim3(8, 16, 8), 256, LDSB, stream>>>(P, vT, sums, out);
}

// Round 8
// 294.324 us; speedup vs baseline: 1.0716x; 1.0716x over previous
//
#include <hip/hip_runtime.h>
#include <hip/hip_bf16.h>
#include <stdint.h>

typedef __attribute__((ext_vector_type(4))) float f32x4;
typedef __attribute__((ext_vector_type(8))) short s16x8;

#define MFMA(a, b, c) __builtin_amdgcn_mfma_f32_16x16x32_bf16((a), (b), (c), 0, 0, 0)

__device__ __forceinline__ ushort f2bf(float f) {
  union { float f; uint32_t u; } v; v.f = f;
  uint32_t r = v.u + 0x7FFFu + ((v.u >> 16) & 1u);
  return (ushort)(r >> 16);
}

__device__ __forceinline__ void gload_lds16(const ushort* g, short* l) {
  __builtin_amdgcn_global_load_lds(
      (const __attribute__((address_space(1))) uint32_t*)g,
      (__attribute__((address_space(3))) uint32_t*)l, 16, 0, 0);
}

// generic bijective XCD chunk swizzle; valid when nwg % 8 == 0, q = nwg/8
__device__ __forceinline__ int xcd_swz(int flat, int q) {
  return (flat & 7) * q + (flat >> 3);
}

// Stage a 128x64 bf16 tile into LDS with 256 threads (4 loads/thread).
// LDS dest linear (global_load_lds requirement); T2 swizzle via permuted
// GLOBAL source 16B-slot: phys(r,s) holds global(r, s ^ (r&7)).
__device__ __forceinline__ void stage128(const ushort* __restrict__ g, int ld,
                                         int row0, int k0, short* lbase, int tid) {
  const int w  = tid >> 6;               // 0..3
  const int l  = tid & 63;
  const int lr = l >> 3;                 // row within 8-row group
  const int ls = l & 7;                  // physical 16B slot
  const ushort* gp = g + (size_t)(row0 + lr) * ld + k0 + ((ls ^ lr) << 3);
  short* lp = lbase + l * 8;
#pragma unroll
  for (int i = 0; i < 4; ++i) {
    const int R0 = w * 32 + i * 8;
    gload_lds16(gp + (size_t)R0 * ld, lp + R0 * 64);
  }
}

// 128x128 tile GEMM core (m97 structure): A[M,K]*Bt[N,K]^T, bf16, fp32 acc.
// 256 thr = 4 waves (2M x 2N), wave = 64x64 out = 4x4 frags of 16x16x32.
// SINGLE-buffered 32KB LDS -> 4+ blocks/CU; cross-block wave overlap hides
// the per-step vmcnt(0) barrier drain (m114/m97 mechanism).
__device__ __forceinline__ void gemm_core(
    const ushort* __restrict__ A, int lda, const ushort* __restrict__ Bt, int ldb,
    int m0, int n0, int nk, short* lds, f32x4 acc[4][4])
{
  const int tid  = threadIdx.x;
  const int lane = tid & 63, wid = tid >> 6;
  const int wr = wid >> 1, wc = wid & 1;
  const int fr = lane & 15, kg = lane >> 4;
  const int s0  = (kg ^ (fr & 7)) << 3;        // swizzled slot offset (shorts)
  const int aro = (wr * 64 + fr) * 64;
  const int bro = (wc * 64 + fr) * 64;

  short* As = lds;             // 16KB
  short* Bs = lds + 8192;      // 16KB

#pragma unroll
  for (int i = 0; i < 4; ++i)
#pragma unroll
    for (int j = 0; j < 4; ++j)
      acc[i][j] = (f32x4){0.f, 0.f, 0.f, 0.f};

#pragma unroll 1
  for (int kk = 0; kk < nk; ++kk) {
    __syncthreads();                          // prev-step LDS reads complete
    stage128(A,  lda, m0, kk * 64, As, tid);
    stage128(Bt, ldb, n0, kk * 64, Bs, tid);
    __syncthreads();                          // drains vmcnt(0); tile resident

    s16x8 b[4][2], a[2][2];
#pragma unroll
    for (int ni = 0; ni < 4; ++ni) {
      b[ni][0] = *(const s16x8*)(Bs + bro + ni * 1024 + s0);
      b[ni][1] = *(const s16x8*)(Bs + bro + ni * 1024 + (s0 ^ 32));
    }
#pragma unroll
    for (int mi = 0; mi < 2; ++mi) {
      a[mi][0] = *(const s16x8*)(As + aro + mi * 1024 + s0);
      a[mi][1] = *(const s16x8*)(As + aro + mi * 1024 + (s0 ^ 32));
    }
#pragma unroll
    for (int mi = 0; mi < 2; ++mi)
#pragma unroll
      for (int ni = 0; ni < 4; ++ni) {
        acc[mi][ni] = MFMA(a[mi][0], b[ni][0], acc[mi][ni]);
        acc[mi][ni] = MFMA(a[mi][1], b[ni][1], acc[mi][ni]);
      }
#pragma unroll
    for (int mi = 0; mi < 2; ++mi) {
      a[mi][0] = *(const s16x8*)(As + aro + (2 + mi) * 1024 + s0);
      a[mi][1] = *(const s16x8*)(As + aro + (2 + mi) * 1024 + (s0 ^ 32));
    }
#pragma unroll
    for (int mi = 0; mi < 2; ++mi)
#pragma unroll
      for (int ni = 0; ni < 4; ++ni) {
        acc[2 + mi][ni] = MFMA(a[mi][0], b[ni][0], acc[2 + mi][ni]);
        acc[2 + mi][ni] = MFMA(a[mi][1], b[ni][1], acc[2 + mi][ni]);
      }
  }
}

__global__ void cvt_x(const float* __restrict__ x, ushort* __restrict__ xb)
{
  const size_t i = (size_t)(blockIdx.x * 256 + threadIdx.x) * 4;
  const f32x4 t = *(const f32x4*)(x + i);
  uint2 pk;
  pk.x = (uint32_t)f2bf(t[0]) | ((uint32_t)f2bf(t[1]) << 16);
  pk.y = (uint32_t)f2bf(t[2]) | ((uint32_t)f2bf(t[3]) << 16);
  *(uint2*)(xb + i) = pk;
}

// wt[z][n][k] = bf16(w_z[k][n]);  z: 0=q_wei, 1=k_wei, 2=v_wei
__global__ void cvt_w(const float* __restrict__ kw, const float* __restrict__ qw,
                      const float* __restrict__ vw, ushort* __restrict__ wt)
{
  __shared__ float t[32][33];
  const float* w = (blockIdx.z == 0) ? qw : (blockIdx.z == 1) ? kw : vw;
  const int n0 = blockIdx.x * 32, k0 = blockIdx.y * 32;
  t[threadIdx.y][threadIdx.x] = w[(size_t)(k0 + threadIdx.y) * 1024 + n0 + threadIdx.x];
  __syncthreads();
  wt[(size_t)blockIdx.z * 1048576 + (size_t)(n0 + threadIdx.y) * 1024 + k0 + threadIdx.x] =
      f2bf(t[threadIdx.x][threadIdx.y]);
}

// N = 3072 (q|k|v), M = 16384. grid (24, 128) = 3072 blocks.
// Rectangular XCD map: 8 XCDs = 2 m-groups x 4 n-groups(6 tiles); within an
// XCD m streams (n innermost) -> working set ~1.75MB << 4MB L2.
__global__ __launch_bounds__(256, 4) void gemm_qkv_impl(
    const ushort* __restrict__ xb, const ushort* __restrict__ wt,
    ushort* __restrict__ q, ushort* __restrict__ k, ushort* __restrict__ vT)
{
  __attribute__((aligned(16))) __shared__ short lds[16384];
  const int flat = blockIdx.x + 24 * blockIdx.y;
  const int xcd = flat & 7, c = flat >> 3;          // c in [0,384)
  const int mloc = c / 6, nloc = c - mloc * 6;
  const int m0 = ((xcd & 1) * 64 + mloc) * 128;
  const int n0 = ((xcd >> 1) * 6 + nloc) * 128;
  f32x4 acc[4][4];
  gemm_core(xb, 1024, wt, 1024, m0, n0, 16, lds, acc);

  const int lane = threadIdx.x & 63;
  const int wid = threadIdx.x >> 6;
  const int wr = wid >> 1, wc = wid & 1;
  const int q4 = (lane >> 4) << 2;
  const int fr = lane & 15;
  const int z  = n0 >> 10;                         // uniform per block
  const int cb = (n0 & 1023) + wc * 64 + fr;
  ushort* o = (z == 0) ? q : k;
#pragma unroll
  for (int mi = 0; mi < 4; ++mi)
#pragma unroll
    for (int ni = 0; ni < 4; ++ni)
#pragma unroll
      for (int j = 0; j < 4; ++j) {
        const int r = m0 + wr * 64 + mi * 16 + q4 + j;
        const int c2 = cb + ni * 16;
        const ushort hv = f2bf(acc[mi][ni][j]);
        if (z < 2) o[(size_t)r * 1024 + c2] = hv;
        else       vT[((size_t)(r >> 11) * 1024 + c2) * 2048 + (r & 2047)] = hv;
      }
}

// Fused S-GEMM + softmax-exp (no-max trick): writes unnormalized
// P~ = exp(qk/32 - 10) bf16 dense [b][2048][2048], accumulates row sums.
// grid (16 kt, 16 qt, 8 b) = 2048 blocks; one b per XCD; causal tile skip.
__global__ __launch_bounds__(256, 4) void gemm_sp(
    const ushort* __restrict__ q, const ushort* __restrict__ k,
    ushort* __restrict__ P, float* __restrict__ sums)
{
  __attribute__((aligned(16))) __shared__ short lds[16384];
  const int nf = xcd_swz(blockIdx.x + 16 * (blockIdx.y + 16 * blockIdx.z), 256);
  const int kt = nf & 15, qt = (nf >> 4) & 15, b = nf >> 8;
  if (kt > qt) return;  // causal: whole tile masked
  f32x4 acc[4][4];
  const ushort* qb = q + (size_t)b * (2048 * 1024);
  const ushort* kb = k + (size_t)b * (2048 * 1024);
  gemm_core(qb, 1024, kb, 1024, qt * 128, kt * 128, 16, lds, acc);
  __syncthreads();                          // staging LDS now dead; reuse below
  float* rowsum = (float*)lds;              // [2 wc][128 rows]

  const int tid  = threadIdx.x;
  const int lane = tid & 63, wid = tid >> 6;
  const int wr = wid >> 1, wc = wid & 1;
  const int q4 = (lane >> 4) << 2;
  const int fr = lane & 15;
  const int diag = (kt == qt);
  ushort* Pb = P + ((size_t)b << 22);

#pragma unroll
  for (int mi = 0; mi < 4; ++mi)
#pragma unroll
    for (int j = 0; j < 4; ++j) {
      const int rloc = wr * 64 + mi * 16 + q4 + j;       // row in tile
      const int rg   = qt * 128 + rloc;                   // global q index
      float s = 0.f;
#pragma unroll
      for (int ni = 0; ni < 4; ++ni) {
        const int cg = kt * 128 + wc * 64 + ni * 16 + fr; // global k index
        float e = __expf(acc[mi][ni][j] * 0.03125f - 10.f);
        if (diag && cg > rg) e = 0.f;
        s += e;
        Pb[(size_t)rg * 2048 + cg] = f2bf(e);
      }
      // reduce over the 16 fr lanes (this wave's 64-col stripe)
#pragma unroll
      for (int m = 1; m < 16; m <<= 1) s += __shfl_xor(s, m);
      if (fr == 0) rowsum[wc * 128 + rloc] = s;
    }
  __syncthreads();
  if (tid < 128) {
    const float tot = rowsum[tid] + rowsum[128 + tid];
    atomicAdd(&sums[b * 2048 + qt * 128 + tid], tot);
  }
}

// grid (8 ht, 16 qt, 8 b) = 1024 blocks; one b per XCD; K truncated causally;
// out = (P~ . V) / sums[row].
__global__ __launch_bounds__(256, 4) void gemm_pv(
    const ushort* __restrict__ P, const ushort* __restrict__ vT,
    const float* __restrict__ sums, float* __restrict__ out)
{
  __attribute__((aligned(16))) __shared__ short lds[16384];
  const int nf = xcd_swz(blockIdx.x + 8 * (blockIdx.y + 16 * blockIdx.z), 128);
  const int ht = nf & 7, qt = (nf >> 3) & 15, b = nf >> 7;
  f32x4 acc[4][4];
  const ushort* Pb = P  + ((size_t)b << 22);           // dense [2048][2048]
  const ushort* Vb = vT + (size_t)b * (1024 * 2048);
  gemm_core(Pb, 2048, Vb, 2048, qt * 128, ht * 128, (qt + 1) * 2, lds, acc);

  float* ob = out + (size_t)b * 2097152;
  const int lane = threadIdx.x & 63;
  const int wid = threadIdx.x >> 6;
  const int wr = wid >> 1, wc = wid & 1;
  const int r0 = qt * 128 + wr * 64 + ((lane >> 4) << 2);
  const int c0 = ht * 128 + wc * 64 + (lane & 15);
#pragma unroll
  for (int mi = 0; mi < 4; ++mi)
#pragma unroll
    for (int j = 0; j < 4; ++j) {
      const int r = r0 + mi * 16 + j;
      const float inv = 1.0f / sums[b * 2048 + r];
#pragma unroll
      for (int ni = 0; ni < 4; ++ni)
        ob[(size_t)r * 1024 + (c0 + ni * 16)] = acc[mi][ni][j] * inv;
    }
}

extern "C" void kernel_launch(void* const* d_in, const int* in_sizes, int n_in,
                              void* d_out, int out_size, void* d_ws, size_t ws_size,
                              hipStream_t stream)
{
  const float* x  = (const float*)d_in[0];
  const float* kw = (const float*)d_in[1];
  const float* qw = (const float*)d_in[2];
  const float* vw = (const float*)d_in[3];
  float* out = (float*)d_out;
  char* ws = (char*)d_ws;

  ushort* xb   = (ushort*)ws;                  // 32MB; aliases P~ (consumed first)
  ushort* P    = (ushort*)ws;                  // 64MB dense bf16 P~ [8][2048][2048]
  float*  sums = (float*)(ws + 67108864);      // 64KB row sums [8][2048]
  ushort* wt   = (ushort*)(ws + 67174400);     // 6MB  transposed bf16 weights [z][n][k]
  ushort* q    = (ushort*)(ws + 73465856);     // 32MB
  ushort* k    = (ushort*)(ws + 107020288);    // 32MB
  ushort* vT   = (ushort*)(ws + 140574720);    // 32MB [B][HS][T]

  hipMemsetAsync(sums, 0, 8 * 2048 * sizeof(float), stream);
  cvt_x<<<16384, 256, 0, stream>>>(x, xb);
  cvt_w<<<dim3(32, 32, 3), dim3(32, 32), 0, stream>>>(kw, qw, vw, wt);
  gemm_qkv_impl<<<dim3(24, 128), 256, 0, stream>>>(xb, wt, q, k, vT);
  gemm_sp<<<dim3(16, 16, 8), 256, 0, stream>>>(q, k, P, sums);
  gemm_pv<<<dim3(8, 16, 8), 256, 0, stream>>>(P, vT, sums, out);
}

// Round 9
// 293.006 us; speedup vs baseline: 1.0765x; 1.0045x over previous
//
#include <hip/hip_runtime.h>
#include <hip/hip_bf16.h>
#include <stdint.h>

typedef __attribute__((ext_vector_type(4))) float f32x4;
typedef __attribute__((ext_vector_type(8))) short s16x8;

#define BARRIER() asm volatile("s_barrier" ::: "memory")
#define WAITV8()  asm volatile("s_waitcnt vmcnt(8)" ::: "memory")
#define WAITV4()  asm volatile("s_waitcnt vmcnt(4)" ::: "memory")
#define WAITV0()  asm volatile("s_waitcnt vmcnt(0)" ::: "memory")
#define LGKM0()   asm volatile("s_waitcnt lgkmcnt(0)" ::: "memory")
#define MFMA(a, b, c) __builtin_amdgcn_mfma_f32_16x16x32_bf16((a), (b), (c), 0, 0, 0)

__device__ __forceinline__ ushort f2bf(float f) {
  union { float f; uint32_t u; } v; v.f = f;
  uint32_t r = v.u + 0x7FFFu + ((v.u >> 16) & 1u);
  return (ushort)(r >> 16);
}

__device__ __forceinline__ void gload_lds16(const ushort* g, short* l) {
  __builtin_amdgcn_global_load_lds(
      (const __attribute__((address_space(1))) uint32_t*)g,
      (__attribute__((address_space(3))) uint32_t*)l, 16, 0, 0);
}

// generic bijective XCD chunk swizzle; valid when nwg % 8 == 0, q = nwg/8
__device__ __forceinline__ int xcd_swz(int flat, int q) {
  return (flat & 7) * q + (flat >> 3);
}

// ---------------- 128^2 core (R8, proven) for sp/pv ----------------

__device__ __forceinline__ void stage128(const ushort* __restrict__ g, int ld,
                                         int row0, int k0, short* lbase, int tid) {
  const int w  = tid >> 6;
  const int l  = tid & 63;
  const int lr = l >> 3;
  const int ls = l & 7;
  const ushort* gp = g + (size_t)(row0 + lr) * ld + k0 + ((ls ^ lr) << 3);
  short* lp = lbase + l * 8;
#pragma unroll
  for (int i = 0; i < 4; ++i) {
    const int R0 = w * 32 + i * 8;
    gload_lds16(gp + (size_t)R0 * ld, lp + R0 * 64);
  }
}

__device__ __forceinline__ void gemm_core(
    const ushort* __restrict__ A, int lda, const ushort* __restrict__ Bt, int ldb,
    int m0, int n0, int nk, short* lds, f32x4 acc[4][4])
{
  const int tid  = threadIdx.x;
  const int lane = tid & 63, wid = tid >> 6;
  const int wr = wid >> 1, wc = wid & 1;
  const int fr = lane & 15, kg = lane >> 4;
  const int s0  = (kg ^ (fr & 7)) << 3;
  const int aro = (wr * 64 + fr) * 64;
  const int bro = (wc * 64 + fr) * 64;

  short* As = lds;
  short* Bs = lds + 8192;

#pragma unroll
  for (int i = 0; i < 4; ++i)
#pragma unroll
    for (int j = 0; j < 4; ++j)
      acc[i][j] = (f32x4){0.f, 0.f, 0.f, 0.f};

#pragma unroll 1
  for (int kk = 0; kk < nk; ++kk) {
    __syncthreads();
    stage128(A,  lda, m0, kk * 64, As, tid);
    stage128(Bt, ldb, n0, kk * 64, Bs, tid);
    __syncthreads();

    s16x8 b[4][2], a[2][2];
#pragma unroll
    for (int ni = 0; ni < 4; ++ni) {
      b[ni][0] = *(const s16x8*)(Bs + bro + ni * 1024 + s0);
      b[ni][1] = *(const s16x8*)(Bs + bro + ni * 1024 + (s0 ^ 32));
    }
#pragma unroll
    for (int mi = 0; mi < 2; ++mi) {
      a[mi][0] = *(const s16x8*)(As + aro + mi * 1024 + s0);
      a[mi][1] = *(const s16x8*)(As + aro + mi * 1024 + (s0 ^ 32));
    }
#pragma unroll
    for (int mi = 0; mi < 2; ++mi)
#pragma unroll
      for (int ni = 0; ni < 4; ++ni) {
        acc[mi][ni] = MFMA(a[mi][0], b[ni][0], acc[mi][ni]);
        acc[mi][ni] = MFMA(a[mi][1], b[ni][1], acc[mi][ni]);
      }
#pragma unroll
    for (int mi = 0; mi < 2; ++mi) {
      a[mi][0] = *(const s16x8*)(As + aro + (2 + mi) * 1024 + s0);
      a[mi][1] = *(const s16x8*)(As + aro + (2 + mi) * 1024 + (s0 ^ 32));
    }
#pragma unroll
    for (int mi = 0; mi < 2; ++mi)
#pragma unroll
      for (int ni = 0; ni < 4; ++ni) {
        acc[2 + mi][ni] = MFMA(a[mi][0], b[ni][0], acc[2 + mi][ni]);
        acc[2 + mi][ni] = MFMA(a[mi][1], b[ni][1], acc[2 + mi][ni]);
      }
  }
}

// ---------------- 256^2 m201-style 8-phase core (qkv) ----------------
// 512 thr = 8 waves (2M x 4N); wave = 128x64 = 8x4 frags. LDS 128KB:
// A: 4 half-regions [slot(2)][half(2)] of 16KB; B likewise at +32768 shorts.
// Per iter t: consume tiles E=2t (slot0, ph1-4) and O=2t+1 (slot1, ph5-8).
// Stage exactly ONE 128x64 half per phase (2 gloads/thread):
//   ph1:A(O)h1  ph2:B(O)h1  ph3:B(2t+2)h0  ph4:A(2t+2)h0
//   ph5:A(2t+2)h1 ph6:B(2t+2)h1 ph7:B(2t+3)h0 ph8:A(2t+3)h0
// Gates vmcnt(4) at ph4/ph8 drain exactly the halves read in the next 4
// phases. Seal proof: every stage targets a region whose last ds_read was
// >= 1 phase earlier (sealed by that phase's lgkm0 + end-barrier).

__device__ __forceinline__ void stage_half(const ushort* __restrict__ g, int ld,
                                           int grow0, int k0, short* lbase, int tid) {
#pragma unroll
  for (int i = 0; i < 2; ++i) {
    const int idx = i * 512 + tid;
    const int r = idx >> 3;
    const int s = tid & 7;
    gload_lds16(g + (size_t)(grow0 + r) * ld + k0 + ((s ^ (r & 7)) << 3),
                lbase + idx * 8);
  }
}

#define QMFMA(mbase, nbase, bq)                                              \
  __builtin_amdgcn_s_setprio(1);                                             \
  _Pragma("unroll")                                                          \
  for (int m = 0; m < 4; ++m) {                                              \
    _Pragma("unroll")                                                        \
    for (int n = 0; n < 2; ++n) {                                            \
      acc[(mbase) + m][(nbase) + n] =                                        \
          MFMA(a[m][0], bq[n][0], acc[(mbase) + m][(nbase) + n]);            \
      acc[(mbase) + m][(nbase) + n] =                                        \
          MFMA(a[m][1], bq[n][1], acc[(mbase) + m][(nbase) + n]);            \
    }                                                                        \
  }                                                                          \
  __builtin_amdgcn_s_setprio(0);

__device__ __forceinline__ void gemm_core256(
    const ushort* __restrict__ A, int lda, const ushort* __restrict__ Bt, int ldb,
    int m0, int n0, int nk, short* lds, f32x4 acc[8][4])
{
  const int tid  = threadIdx.x;
  const int lane = tid & 63, wid = tid >> 6;
  const int wr = wid >> 2, wc = wid & 3;
  const int fr = lane & 15, kg = lane >> 4;
  const int s0  = (kg ^ (fr & 7)) << 3;
  const int aro = fr * 64;
  const int bro = (wc & 1) * 4096 + fr * 64;

#define ASL(s, h) (lds + ((s) * 2 + (h)) * 8192)
#define BSL(s, h) (lds + 32768 + ((s) * 2 + (h)) * 8192)
  short* const Aw[2] = { ASL(0, wr), ASL(1, wr) };                 // wave's A half
  short* const Bw[2] = { BSL(0, (wc >> 1)), BSL(1, (wc >> 1)) };   // wave's B half

#pragma unroll
  for (int i = 0; i < 8; ++i)
#pragma unroll
    for (int j = 0; j < 4; ++j)
      acc[i][j] = (f32x4){0.f, 0.f, 0.f, 0.f};

  // prologue: tiles 0 and 1 fully staged (16 loads/thread); drain tile 0.
  stage_half(A,  lda, m0,       0,  ASL(0, 0), tid);
  stage_half(A,  lda, m0 + 128, 0,  ASL(0, 1), tid);
  stage_half(Bt, ldb, n0,       0,  BSL(0, 0), tid);
  stage_half(Bt, ldb, n0 + 128, 0,  BSL(0, 1), tid);
  stage_half(A,  lda, m0,       64, ASL(1, 0), tid);
  stage_half(A,  lda, m0 + 128, 64, ASL(1, 1), tid);
  stage_half(Bt, ldb, n0,       64, BSL(1, 0), tid);
  stage_half(Bt, ldb, n0 + 128, 64, BSL(1, 1), tid);
  WAITV8();
  BARRIER();

  const int niter = nk >> 1;
#pragma unroll 1
  for (int t = 0; t < niter; ++t) {
    const int kO  = (2 * t + 1) * 64;
    const int kN0 = (2 * t + 2) * 64;
    const int kN1 = (2 * t + 3) * 64;
    const bool more = (t + 1 < niter);
    s16x8 a[4][2], b01[2][2], b23[2][2];

    // ---- ph1: tile E reads b01 + a[0:4]; stage A(O)h1
#pragma unroll
    for (int n = 0; n < 2; ++n) {
      b01[n][0] = *(const s16x8*)(Bw[0] + bro + n * 1024 + s0);
      b01[n][1] = *(const s16x8*)(Bw[0] + bro + n * 1024 + (s0 ^ 32));
    }
#pragma unroll
    for (int m = 0; m < 4; ++m) {
      a[m][0] = *(const s16x8*)(Aw[0] + aro + m * 1024 + s0);
      a[m][1] = *(const s16x8*)(Aw[0] + aro + m * 1024 + (s0 ^ 32));
    }
    if (t > 0) stage_half(A, lda, m0 + 128, kO, ASL(1, 1), tid);
    BARRIER(); LGKM0();
    QMFMA(0, 0, b01);
    BARRIER();

    // ---- ph2: b23; stage B(O)h1
#pragma unroll
    for (int n = 0; n < 2; ++n) {
      b23[n][0] = *(const s16x8*)(Bw[0] + bro + (2 + n) * 1024 + s0);
      b23[n][1] = *(const s16x8*)(Bw[0] + bro + (2 + n) * 1024 + (s0 ^ 32));
    }
    if (t > 0) stage_half(Bt, ldb, n0 + 128, kO, BSL(1, 1), tid);
    BARRIER(); LGKM0();
    QMFMA(0, 2, b23);
    BARRIER();

    // ---- ph3: a[4:8]; stage B(2t+2)h0
#pragma unroll
    for (int m = 0; m < 4; ++m) {
      a[m][0] = *(const s16x8*)(Aw[0] + aro + (4 + m) * 1024 + s0);
      a[m][1] = *(const s16x8*)(Aw[0] + aro + (4 + m) * 1024 + (s0 ^ 32));
    }
    if (more) stage_half(Bt, ldb, n0, kN0, BSL(0, 0), tid);
    BARRIER(); LGKM0();
    QMFMA(4, 2, b23);
    BARRIER();

    // ---- ph4: stage A(2t+2)h0; gate vmcnt(4)
    if (more) stage_half(A, lda, m0, kN0, ASL(0, 0), tid);
    BARRIER();
    QMFMA(4, 0, b01);
    if (more) { WAITV4(); } else { WAITV0(); }
    BARRIER();

    // ---- ph5: tile O reads b01 + a[0:4]; stage A(2t+2)h1
#pragma unroll
    for (int n = 0; n < 2; ++n) {
      b01[n][0] = *(const s16x8*)(Bw[1] + bro + n * 1024 + s0);
      b01[n][1] = *(const s16x8*)(Bw[1] + bro + n * 1024 + (s0 ^ 32));
    }
#pragma unroll
    for (int m = 0; m < 4; ++m) {
      a[m][0] = *(const s16x8*)(Aw[1] + aro + m * 1024 + s0);
      a[m][1] = *(const s16x8*)(Aw[1] + aro + m * 1024 + (s0 ^ 32));
    }
    if (more) stage_half(A, lda, m0 + 128, kN0, ASL(0, 1), tid);
    BARRIER(); LGKM0();
    QMFMA(0, 0, b01);
    BARRIER();

    // ---- ph6: b23; stage B(2t+2)h1
#pragma unroll
    for (int n = 0; n < 2; ++n) {
      b23[n][0] = *(const s16x8*)(Bw[1] + bro + (2 + n) * 1024 + s0);
      b23[n][1] = *(const s16x8*)(Bw[1] + bro + (2 + n) * 1024 + (s0 ^ 32));
    }
    if (more) stage_half(Bt, ldb, n0 + 128, kN0, BSL(0, 1), tid);
    BARRIER(); LGKM0();
    QMFMA(0, 2, b23);
    BARRIER();

    // ---- ph7: a[4:8]; stage B(2t+3)h0
#pragma unroll
    for (int m = 0; m < 4; ++m) {
      a[m][0] = *(const s16x8*)(Aw[1] + aro + (4 + m) * 1024 + s0);
      a[m][1] = *(const s16x8*)(Aw[1] + aro + (4 + m) * 1024 + (s0 ^ 32));
    }
    if (more) stage_half(Bt, ldb, n0, kN1, BSL(1, 0), tid);
    BARRIER(); LGKM0();
    QMFMA(4, 2, b23);
    BARRIER();

    // ---- ph8: stage A(2t+3)h0; gate vmcnt(4)
    if (more) stage_half(A, lda, m0, kN1, ASL(1, 0), tid);
    BARRIER();
    QMFMA(4, 0, b01);
    if (more) { WAITV4(); } else { WAITV0(); }
    BARRIER();
  }
#undef ASL
#undef BSL
}

__global__ void cvt_x(const float* __restrict__ x, ushort* __restrict__ xb)
{
  const size_t i = (size_t)(blockIdx.x * 256 + threadIdx.x) * 4;
  const f32x4 t = *(const f32x4*)(x + i);
  uint2 pk;
  pk.x = (uint32_t)f2bf(t[0]) | ((uint32_t)f2bf(t[1]) << 16);
  pk.y = (uint32_t)f2bf(t[2]) | ((uint32_t)f2bf(t[3]) << 16);
  *(uint2*)(xb + i) = pk;
}

// wt[z][n][k] = bf16(w_z[k][n]);  z: 0=q_wei, 1=k_wei, 2=v_wei
__global__ void cvt_w(const float* __restrict__ kw, const float* __restrict__ qw,
                      const float* __restrict__ vw, ushort* __restrict__ wt)
{
  __shared__ float t[32][33];
  const float* w = (blockIdx.z == 0) ? qw : (blockIdx.z == 1) ? kw : vw;
  const int n0 = blockIdx.x * 32, k0 = blockIdx.y * 32;
  t[threadIdx.y][threadIdx.x] = w[(size_t)(k0 + threadIdx.y) * 1024 + n0 + threadIdx.x];
  __syncthreads();
  wt[(size_t)blockIdx.z * 1048576 + (size_t)(n0 + threadIdx.y) * 1024 + k0 + threadIdx.x] =
      f2bf(t[threadIdx.x][threadIdx.y]);
}

// N = 3072 (q|k|v), M = 16384, 256^2 tiles: grid (12, 64) = 768 blocks.
// Rect XCD map: 8 XCDs = 2 m-groups(32 tiles) x 4 n-groups(3 tiles);
// per XCD B-chunk 1.5MB resident in L2, A streams.
__global__ __launch_bounds__(512) void gemm_qkv256(
    const ushort* __restrict__ xb, const ushort* __restrict__ wt,
    ushort* __restrict__ q, ushort* __restrict__ k, ushort* __restrict__ vT)
{
  extern __shared__ short lds[];
  const int flat = blockIdx.x + 12 * blockIdx.y;
  const int xcd = flat & 7, c = flat >> 3;          // c in [0,96)
  const int mloc = c / 3, nloc = c - mloc * 3;
  const int m0 = ((xcd & 1) * 32 + mloc) * 256;
  const int n0 = ((xcd >> 1) * 3 + nloc) * 256;
  f32x4 acc[8][4];
  gemm_core256(xb, 1024, wt, 1024, m0, n0, 16, lds, acc);

  const int lane = threadIdx.x & 63;
  const int wid = threadIdx.x >> 6;
  const int wr = wid >> 2, wc = wid & 3;
  const int q4 = (lane >> 4) << 2;
  const int fr = lane & 15;
  const int z  = n0 >> 10;                         // uniform per block
  const int cb = (n0 & 1023) + wc * 64 + fr;
  ushort* o = (z == 0) ? q : k;
#pragma unroll
  for (int mi = 0; mi < 8; ++mi)
#pragma unroll
    for (int ni = 0; ni < 4; ++ni)
#pragma unroll
      for (int j = 0; j < 4; ++j) {
        const int r = m0 + wr * 128 + mi * 16 + q4 + j;
        const int c2 = cb + ni * 16;
        const ushort hv = f2bf(acc[mi][ni][j]);
        if (z < 2) o[(size_t)r * 1024 + c2] = hv;
        else       vT[((size_t)(r >> 11) * 1024 + c2) * 2048 + (r & 2047)] = hv;
      }
}

// Fused S-GEMM + softmax-exp (no-max trick): writes unnormalized
// P~ = exp(qk/32 - 10) bf16 dense [b][2048][2048], accumulates row sums.
// grid (16 kt, 16 qt, 8 b) = 2048 blocks; causal tile skip.
__global__ __launch_bounds__(256, 4) void gemm_sp(
    const ushort* __restrict__ q, const ushort* __restrict__ k,
    ushort* __restrict__ P, float* __restrict__ sums)
{
  __attribute__((aligned(16))) __shared__ short lds[16384];
  const int nf = xcd_swz(blockIdx.x + 16 * (blockIdx.y + 16 * blockIdx.z), 256);
  const int kt = nf & 15, qt = (nf >> 4) & 15, b = nf >> 8;
  if (kt > qt) return;  // causal: whole tile masked
  f32x4 acc[4][4];
  const ushort* qb = q + (size_t)b * (2048 * 1024);
  const ushort* kb = k + (size_t)b * (2048 * 1024);
  gemm_core(qb, 1024, kb, 1024, qt * 128, kt * 128, 16, lds, acc);
  __syncthreads();                          // staging LDS now dead; reuse below
  float* rowsum = (float*)lds;              // [2 wc][128 rows]

  const int tid  = threadIdx.x;
  const int lane = tid & 63, wid = tid >> 6;
  const int wr = wid >> 1, wc = wid & 1;
  const int q4 = (lane >> 4) << 2;
  const int fr = lane & 15;
  const int diag = (kt == qt);
  ushort* Pb = P + ((size_t)b << 22);

#pragma unroll
  for (int mi = 0; mi < 4; ++mi)
#pragma unroll
    for (int j = 0; j < 4; ++j) {
      const int rloc = wr * 64 + mi * 16 + q4 + j;       // row in tile
      const int rg   = qt * 128 + rloc;                   // global q index
      float s = 0.f;
#pragma unroll
      for (int ni = 0; ni < 4; ++ni) {
        const int cg = kt * 128 + wc * 64 + ni * 16 + fr; // global k index
        float e = __expf(acc[mi][ni][j] * 0.03125f - 10.f);
        if (diag && cg > rg) e = 0.f;
        s += e;
        Pb[(size_t)rg * 2048 + cg] = f2bf(e);
      }
#pragma unroll
      for (int m = 1; m < 16; m <<= 1) s += __shfl_xor(s, m);
      if (fr == 0) rowsum[wc * 128 + rloc] = s;
    }
  __syncthreads();
  if (tid < 128) {
    const float tot = rowsum[tid] + rowsum[128 + tid];
    atomicAdd(&sums[b * 2048 + qt * 128 + tid], tot);
  }
}

// grid (8 ht, 16 qt, 8 b) = 1024 blocks; K truncated causally;
// out = (P~ . V) / sums[row].
__global__ __launch_bounds__(256, 4) void gemm_pv(
    const ushort* __restrict__ P, const ushort* __restrict__ vT,
    const float* __restrict__ sums, float* __restrict__ out)
{
  __attribute__((aligned(16))) __shared__ short lds[16384];
  const int nf = xcd_swz(blockIdx.x + 8 * (blockIdx.y + 16 * blockIdx.z), 128);
  const int ht = nf & 7, qt = (nf >> 3) & 15, b = nf >> 7;
  f32x4 acc[4][4];
  const ushort* Pb = P  + ((size_t)b << 22);           // dense [2048][2048]
  const ushort* Vb = vT + (size_t)b * (1024 * 2048);
  gemm_core(Pb, 2048, Vb, 2048, qt * 128, ht * 128, (qt + 1) * 2, lds, acc);

  float* ob = out + (size_t)b * 2097152;
  const int lane = threadIdx.x & 63;
  const int wid = threadIdx.x >> 6;
  const int wr = wid >> 1, wc = wid & 1;
  const int r0 = qt * 128 + wr * 64 + ((lane >> 4) << 2);
  const int c0 = ht * 128 + wc * 64 + (lane & 15);
#pragma unroll
  for (int mi = 0; mi < 4; ++mi)
#pragma unroll
    for (int j = 0; j < 4; ++j) {
      const int r = r0 + mi * 16 + j;
      const float inv = 1.0f / sums[b * 2048 + r];
#pragma unroll
      for (int ni = 0; ni < 4; ++ni)
        ob[(size_t)r * 1024 + (c0 + ni * 16)] = acc[mi][ni][j] * inv;
    }
}

extern "C" void kernel_launch(void* const* d_in, const int* in_sizes, int n_in,
                              void* d_out, int out_size, void* d_ws, size_t ws_size,
                              hipStream_t stream)
{
  const float* x  = (const float*)d_in[0];
  const float* kw = (const float*)d_in[1];
  const float* qw = (const float*)d_in[2];
  const float* vw = (const float*)d_in[3];
  float* out = (float*)d_out;
  char* ws = (char*)d_ws;

  ushort* xb   = (ushort*)ws;                  // 32MB; aliases P~ (consumed first)
  ushort* P    = (ushort*)ws;                  // 64MB dense bf16 P~ [8][2048][2048]
  float*  sums = (float*)(ws + 67108864);      // 64KB row sums [8][2048]
  ushort* wt   = (ushort*)(ws + 67174400);     // 6MB  transposed bf16 weights [z][n][k]
  ushort* q    = (ushort*)(ws + 73465856);     // 32MB
  ushort* k    = (ushort*)(ws + 107020288);    // 32MB
  ushort* vT   = (ushort*)(ws + 140574720);    // 32MB [B][HS][T]

  const int LDSB = 131072;  // 128KB dynamic LDS for the 8-phase qkv core
  hipFuncSetAttribute((const void*)gemm_qkv256, hipFuncAttributeMaxDynamicSharedMemorySize, LDSB);

  hipMemsetAsync(sums, 0, 8 * 2048 * sizeof(float), stream);
  cvt_x<<<16384, 256, 0, stream>>>(x, xb);
  cvt_w<<<dim3(32, 32, 3), dim3(32, 32), 0, stream>>>(kw, qw, vw, wt);
  gemm_qkv256<<<dim3(12, 64), 512, LDSB, stream>>>(xb, wt, q, k, vT);
  gemm_sp<<<dim3(16, 16, 8), 256, 0, stream>>>(q, k, P, sums);
  gemm_pv<<<dim3(8, 16, 8), 256, 0, stream>>>(P, vT, sums, out);
}